// Round 19
// baseline (41.131 us; speedup 1.0000x reference)
//
#include <hip/hip_runtime.h>
#include <stdint.h>

typedef __attribute__((ext_vector_type(8))) short short8;
typedef __attribute__((ext_vector_type(4))) float f32x4;

#define BIG 4.0f   // score shift: s' = BIG - 0.5||w||^2 + dot > 0 always

// fp32 -> bf16 bits, round-to-nearest-even
static __device__ __forceinline__ short f2bf(float f) {
    union { float f; uint32_t u; } v; v.f = f;
    uint32_t u = v.u;
    return (short)((u + 0x7FFFu + ((u >> 16) & 1u)) >> 16);
}

// ws layout: ws[4096 .. 4096+256) per-block loss partials. No codebook
// staging buffer: the codebook is converted in-block (prep kernel removed).

// Main fused VQ (R17 structure, prep folded in). 256 blocks x 512 threads
// (8 waves); full 128 KB codebook converted fp32->bf16 IN-BLOCK into
// fragment-major LDS (16 passes x ds_write_b128, norms via 16-lane shfl);
// ONE barrier. Write-behind: batch-B raw loads issued before batch-A
// epilogue; batch-A q-writes interleaved into batch-B's unrolled compute.
// launch_bounds arg2 CALIBRATION: 2 -> VGPR cap 128; 4 -> cap 64 + spill.
__global__ __launch_bounds__(512, 2)
void vq_main_kernel(const float* __restrict__ lat,
                    const float* __restrict__ w0, const float* __restrict__ w1,
                    const float* __restrict__ w2, const float* __restrict__ w3,
                    float* __restrict__ out, float* __restrict__ ws) {
    __shared__ __align__(16) short lw[65536];   // 128 KB codebook, fragment-major:
    // 16B unit (nt 0..31, ks 0..3, lane=lh*16+lr) at ((nt*4+ks)*64+lane)*16
    // holds code nt*16+lr, dims [ks*32+lh*8, +8)
    __shared__ float lwsq[512];                  // BIG - 0.5*||w||^2
    __shared__ float slsum[8];

    const int bid   = blockIdx.x;            // 0..255
    const int g     = bid >> 6;              // 0..3
    const int tbase = (bid & 63) * 512;      // token base within group
    const float* wg = (g == 0) ? w0 : (g == 1) ? w1 : (g == 2) ? w2 : w3;

    const int t    = threadIdx.x;            // 0..511
    const int wave = t >> 6;                 // 0..7
    const int l    = t & 63;
    const int lr   = l & 15;
    const int lh   = l >> 4;
    const int col  = (l & 31) * 4;
    const uint32_t invlr = 511 - lr;

    // ---- in-block codebook convert + stage (replaces prep kernel) ----
    // pass p: code c = p*32 + (t>>4); lane u = t&15 covers dims [u*8, u*8+8).
    // Reads are coalesced (16 lanes x 32B = 512B contiguous per code);
    // fp32 codebook is L2-resident (256KB/group shared by 64 blocks).
    {
        const int u   = t & 15;
        const int ks2 = u >> 2, lh2 = u & 3;
        #pragma unroll 4
        for (int p = 0; p < 16; p++) {
            int c   = p * 32 + (t >> 4);
            int nt2 = c >> 4, lr2 = c & 15;
            const float* src = wg + (size_t)c * 128 + u * 8;
            float4 v0 = *(const float4*)(src);
            float4 v1 = *(const float4*)(src + 4);
            float s = v0.x*v0.x + v0.y*v0.y + v0.z*v0.z + v0.w*v0.w
                    + v1.x*v1.x + v1.y*v1.y + v1.z*v1.z + v1.w*v1.w;
            short8 b;
            b[0] = f2bf(v0.x); b[1] = f2bf(v0.y); b[2] = f2bf(v0.z); b[3] = f2bf(v0.w);
            b[4] = f2bf(v1.x); b[5] = f2bf(v1.y); b[6] = f2bf(v1.z); b[7] = f2bf(v1.w);
            *(short8*)((char*)lw + (size_t)(((nt2 * 4 + ks2) * 64 + lh2 * 16 + lr2) * 16)) = b;
            s += __shfl_xor(s, 1); s += __shfl_xor(s, 2);
            s += __shfl_xor(s, 4); s += __shfl_xor(s, 8);
            if (u == 0) lwsq[c] = BIG - 0.5f * s;
        }
    }

    const char* lwb = (const char*)lw + l * 16;
    const int wtok = tbase + wave * 64;

    auto load_convert = [&](short8 (&fr)[2][4], float (&xsp)[2], int wt) {
        #pragma unroll
        for (int mt = 0; mt < 2; mt++) {
            int token = wt + mt * 16 + lr;
            const float* xp = lat + (size_t)token * 512 + g * 128 + lh * 8;
            float part = 0.f;
            #pragma unroll
            for (int ks = 0; ks < 4; ks++) {
                float4 v0 = *(const float4*)(xp + ks * 32);
                float4 v1 = *(const float4*)(xp + ks * 32 + 4);
                part += v0.x*v0.x + v0.y*v0.y + v0.z*v0.z + v0.w*v0.w
                      + v1.x*v1.x + v1.y*v1.y + v1.z*v1.z + v1.w*v1.w;
                short8 a;
                a[0] = f2bf(v0.x); a[1] = f2bf(v0.y); a[2] = f2bf(v0.z); a[3] = f2bf(v0.w);
                a[4] = f2bf(v1.x); a[5] = f2bf(v1.y); a[6] = f2bf(v1.z); a[7] = f2bf(v1.w);
                fr[mt][ks] = a;
            }
            part += __shfl_xor(part, 16);
            part += __shfl_xor(part, 32);
            xsp[mt] = part;
        }
    };

    auto compute = [&](short8 (&af)[2][4], uint32_t (&rk)[8]) {
        short8 p0 = *(const short8*)(lwb);
        short8 p1 = *(const short8*)(lwb + 1024);
        short8 p2 = *(const short8*)(lwb + 2048);
        short8 p3 = *(const short8*)(lwb + 3072);
        float  ph = lwsq[lr];
        #pragma unroll 4
        for (int nt = 0; nt < 32; nt++) {
            short8 c0 = p0, c1 = p1, c2 = p2, c3 = p3;
            float  hn = ph;
            const char* nb = lwb + ((nt + 1) & 31) * 4096;
            p0 = *(const short8*)(nb);
            p1 = *(const short8*)(nb + 1024);
            p2 = *(const short8*)(nb + 2048);
            p3 = *(const short8*)(nb + 3072);
            ph = lwsq[(((nt + 1) & 31) << 4) + lr];
            const uint32_t invc = invlr - (uint32_t)(nt * 16);
            __builtin_amdgcn_s_setprio(1);
            f32x4 acc0 = {hn, hn, hn, hn};
            f32x4 acc1 = {hn, hn, hn, hn};
            acc0 = __builtin_amdgcn_mfma_f32_16x16x32_bf16(af[0][0], c0, acc0, 0, 0, 0);
            acc0 = __builtin_amdgcn_mfma_f32_16x16x32_bf16(af[0][1], c1, acc0, 0, 0, 0);
            acc0 = __builtin_amdgcn_mfma_f32_16x16x32_bf16(af[0][2], c2, acc0, 0, 0, 0);
            acc0 = __builtin_amdgcn_mfma_f32_16x16x32_bf16(af[0][3], c3, acc0, 0, 0, 0);
            acc1 = __builtin_amdgcn_mfma_f32_16x16x32_bf16(af[1][0], c0, acc1, 0, 0, 0);
            acc1 = __builtin_amdgcn_mfma_f32_16x16x32_bf16(af[1][1], c1, acc1, 0, 0, 0);
            acc1 = __builtin_amdgcn_mfma_f32_16x16x32_bf16(af[1][2], c2, acc1, 0, 0, 0);
            acc1 = __builtin_amdgcn_mfma_f32_16x16x32_bf16(af[1][3], c3, acc1, 0, 0, 0);
            __builtin_amdgcn_s_setprio(0);
            #pragma unroll
            for (int r = 0; r < 4; r++) {
                rk[r]     = max(rk[r],     (__float_as_uint(acc0[r]) & 0xFFFFFE00u) | invc);
                rk[4 + r] = max(rk[4 + r], (__float_as_uint(acc1[r]) & 0xFFFFFE00u) | invc);
            }
        }
    };

    auto epilogue = [&](uint32_t (&rk)[8], float (&xsp)[2], int wt, float& acc_lsum) {
        int runidx[8];
        #pragma unroll
        for (int i = 0; i < 8; i++) {
            uint32_t k = rk[i];
            k = max(k, (uint32_t)__shfl_xor((int)k, 1));
            k = max(k, (uint32_t)__shfl_xor((int)k, 2));
            k = max(k, (uint32_t)__shfl_xor((int)k, 4));
            k = max(k, (uint32_t)__shfl_xor((int)k, 8));
            rk[i] = k;
            runidx[i] = 511 - (int)(k & 0x1FFu);
        }
        #pragma unroll
        for (int mt = 0; mt < 2; mt++) {
            #pragma unroll
            for (int r = 0; r < 4; r++) {
                int row = lh * 4 + r;
                float xs = __shfl(xsp[mt], (l & 48) | row);
                float val = __uint_as_float(rk[mt * 4 + r] & 0xFFFFFE00u);
                if (lr == 0) acc_lsum += xs + 2.f * BIG - 2.f * val;
            }
        }
        #pragma unroll
        for (int it = 0; it < 16; it++) {
            const int j0 = it * 2, j1 = it * 2 + 1;
            int idx0 = __shfl(runidx[((j0 >> 4) << 2) | (j0 & 3)], ((j0 >> 2) & 3) << 4);
            int idx1 = __shfl(runidx[((j1 >> 4) << 2) | (j1 & 3)], ((j1 >> 2) & 3) << 4);
            int idx  = (l >= 32) ? idx1 : idx0;
            int tloc = it * 2 + (l >> 5);
            float4 v = *(const float4*)(wg + (size_t)idx * 128 + col);
            *(float4*)(out + (size_t)(wt + tloc) * 512 + g * 128 + col) = v;
        }
    };

    short8 fA[2][4], fB[2][4];
    float  xspA[2], xspB[2];
    uint32_t kA[8], kB[8];
    #pragma unroll
    for (int i = 0; i < 8; i++) { kA[i] = 0u; kB[i] = 0u; }

    load_convert(fA, xspA, wtok);        // overlaps codebook convert drain
    __syncthreads();                     // codebook + lwsq resident (only barrier)

    float lsum = 0.f;
    compute(fA, kA);

    // ---- issue batch-B raw loads; they fly during A's reduce + B convert ----
    float4 raw[16];
    #pragma unroll
    for (int mt = 0; mt < 2; mt++) {
        #pragma unroll
        for (int ks = 0; ks < 4; ks++) {
            const float* xp = lat + (size_t)(wtok + 32 + mt * 16 + lr) * 512
                            + g * 128 + lh * 8 + ks * 32;
            raw[mt * 8 + ks * 2]     = *(const float4*)(xp);
            raw[mt * 8 + ks * 2 + 1] = *(const float4*)(xp + 4);
        }
    }

    // ---- argmax + loss for batch A (overlaps raw-load flight) ----
    int runidxA[8];
    #pragma unroll
    for (int i = 0; i < 8; i++) {
        uint32_t k = kA[i];
        k = max(k, (uint32_t)__shfl_xor((int)k, 1));
        k = max(k, (uint32_t)__shfl_xor((int)k, 2));
        k = max(k, (uint32_t)__shfl_xor((int)k, 4));
        k = max(k, (uint32_t)__shfl_xor((int)k, 8));
        kA[i] = k;
        runidxA[i] = 511 - (int)(k & 0x1FFu);
    }
    #pragma unroll
    for (int mt = 0; mt < 2; mt++) {
        #pragma unroll
        for (int r = 0; r < 4; r++) {
            int row = lh * 4 + r;
            float xs = __shfl(xspA[mt], (l & 48) | row);
            float val = __uint_as_float(kA[mt * 4 + r] & 0xFFFFFE00u);
            if (lr == 0) lsum += xs + 2.f * BIG - 2.f * val;
        }
    }
    int widx[16];
    #pragma unroll
    for (int it = 0; it < 16; it++) {
        const int j0 = it * 2, j1 = it * 2 + 1;
        int idx0 = __shfl(runidxA[((j0 >> 4) << 2) | (j0 & 3)], ((j0 >> 2) & 3) << 4);
        int idx1 = __shfl(runidxA[((j1 >> 4) << 2) | (j1 & 3)], ((j1 >> 2) & 3) << 4);
        widx[it] = (l >= 32) ? idx1 : idx0;
    }

    // ---- convert batch B ----
    #pragma unroll
    for (int mt = 0; mt < 2; mt++) {
        float part = 0.f;
        #pragma unroll
        for (int ks = 0; ks < 4; ks++) {
            float4 v0 = raw[mt * 8 + ks * 2];
            float4 v1 = raw[mt * 8 + ks * 2 + 1];
            part += v0.x*v0.x + v0.y*v0.y + v0.z*v0.z + v0.w*v0.w
                  + v1.x*v1.x + v1.y*v1.y + v1.z*v1.z + v1.w*v1.w;
            short8 a;
            a[0] = f2bf(v0.x); a[1] = f2bf(v0.y); a[2] = f2bf(v0.z); a[3] = f2bf(v0.w);
            a[4] = f2bf(v1.x); a[5] = f2bf(v1.y); a[6] = f2bf(v1.z); a[7] = f2bf(v1.w);
            fB[mt][ks] = a;
        }
        part += __shfl_xor(part, 16);
        part += __shfl_xor(part, 32);
        xspB[mt] = part;
    }

    // ---- fused: compute batch B with batch-A q-writes interleaved ----
    {
        short8 p0 = *(const short8*)(lwb);
        short8 p1 = *(const short8*)(lwb + 1024);
        short8 p2 = *(const short8*)(lwb + 2048);
        short8 p3 = *(const short8*)(lwb + 3072);
        float  ph = lwsq[lr];
        float4 vb0, vb1;

#define FUSED_NT(nt)                                                           \
        {                                                                      \
            short8 c0 = p0, c1 = p1, c2 = p2, c3 = p3;                         \
            float  hn = ph;                                                    \
            const char* nb = lwb + (((nt) + 1) & 31) * 4096;                   \
            p0 = *(const short8*)(nb);                                         \
            p1 = *(const short8*)(nb + 1024);                                  \
            p2 = *(const short8*)(nb + 2048);                                  \
            p3 = *(const short8*)(nb + 3072);                                  \
            ph = lwsq[((((nt) + 1) & 31) << 4) + lr];                          \
            const uint32_t invc = invlr - (uint32_t)((nt) * 16);               \
            __builtin_amdgcn_s_setprio(1);                                     \
            f32x4 acc0 = {hn, hn, hn, hn};                                     \
            f32x4 acc1 = {hn, hn, hn, hn};                                     \
            acc0 = __builtin_amdgcn_mfma_f32_16x16x32_bf16(fB[0][0], c0, acc0, 0, 0, 0); \
            acc0 = __builtin_amdgcn_mfma_f32_16x16x32_bf16(fB[0][1], c1, acc0, 0, 0, 0); \
            acc0 = __builtin_amdgcn_mfma_f32_16x16x32_bf16(fB[0][2], c2, acc0, 0, 0, 0); \
            acc0 = __builtin_amdgcn_mfma_f32_16x16x32_bf16(fB[0][3], c3, acc0, 0, 0, 0); \
            acc1 = __builtin_amdgcn_mfma_f32_16x16x32_bf16(fB[1][0], c0, acc1, 0, 0, 0); \
            acc1 = __builtin_amdgcn_mfma_f32_16x16x32_bf16(fB[1][1], c1, acc1, 0, 0, 0); \
            acc1 = __builtin_amdgcn_mfma_f32_16x16x32_bf16(fB[1][2], c2, acc1, 0, 0, 0); \
            acc1 = __builtin_amdgcn_mfma_f32_16x16x32_bf16(fB[1][3], c3, acc1, 0, 0, 0); \
            __builtin_amdgcn_s_setprio(0);                                     \
            kB[0] = max(kB[0], (__float_as_uint(acc0[0]) & 0xFFFFFE00u) | invc); \
            kB[1] = max(kB[1], (__float_as_uint(acc0[1]) & 0xFFFFFE00u) | invc); \
            kB[2] = max(kB[2], (__float_as_uint(acc0[2]) & 0xFFFFFE00u) | invc); \
            kB[3] = max(kB[3], (__float_as_uint(acc0[3]) & 0xFFFFFE00u) | invc); \
            kB[4] = max(kB[4], (__float_as_uint(acc1[0]) & 0xFFFFFE00u) | invc); \
            kB[5] = max(kB[5], (__float_as_uint(acc1[1]) & 0xFFFFFE00u) | invc); \
            kB[6] = max(kB[6], (__float_as_uint(acc1[2]) & 0xFFFFFE00u) | invc); \
            kB[7] = max(kB[7], (__float_as_uint(acc1[3]) & 0xFFFFFE00u) | invc); \
            if (((nt) & 3) == 1) {                                             \
                const int it0 = ((nt) >> 2) * 2;                               \
                vb0 = *(const float4*)(wg + (size_t)widx[it0] * 128 + col);    \
                vb1 = *(const float4*)(wg + (size_t)widx[it0 + 1] * 128 + col);\
            }                                                                  \
            if (((nt) & 3) == 3) {                                             \
                const int it0 = ((nt) >> 2) * 2;                               \
                *(float4*)(out + (size_t)(wtok + it0 * 2 + (l >> 5)) * 512     \
                           + g * 128 + col) = vb0;                             \
                *(float4*)(out + (size_t)(wtok + (it0 + 1) * 2 + (l >> 5)) * 512 \
                           + g * 128 + col) = vb1;                             \
            }                                                                  \
        }
#define FUSED_4(n) FUSED_NT(n) FUSED_NT((n) + 1) FUSED_NT((n) + 2) FUSED_NT((n) + 3)
        FUSED_4(0)  FUSED_4(4)  FUSED_4(8)  FUSED_4(12)
        FUSED_4(16) FUSED_4(20) FUSED_4(24) FUSED_4(28)
#undef FUSED_4
#undef FUSED_NT
    }

    // ---- epilogue batch B (argmax, loss, q-writes) ----
    epilogue(kB, xspB, wtok + 32, lsum);

    // loss: wave partial -> one plain store per block
    lsum += __shfl_xor(lsum, 16);
    lsum += __shfl_xor(lsum, 32);
    if (l == 0) slsum[wave] = lsum;
    __syncthreads();
    if (t == 0) {
        float s = 0.f;
        #pragma unroll
        for (int i = 0; i < 8; i++) s += slsum[i];
        ws[4096 + bid] = s;
    }
}

// Finalize loss — reduce 256 per-block partials
__global__ void vq_finalize_kernel(const float* __restrict__ ws, float* __restrict__ out) {
    __shared__ float s4[4];
    float v = ws[4096 + threadIdx.x];
    #pragma unroll
    for (int m = 1; m < 64; m <<= 1) v += __shfl_xor(v, m);
    if ((threadIdx.x & 63) == 0) s4[threadIdx.x >> 6] = v;
    __syncthreads();
    if (threadIdx.x == 0)
        out[16777216] = 1.25f * (s4[0] + s4[1] + s4[2] + s4[3]) * (1.0f / 4194304.0f);
}

extern "C" void kernel_launch(void* const* d_in, const int* in_sizes, int n_in,
                              void* d_out, int out_size, void* d_ws, size_t ws_size,
                              hipStream_t stream) {
    const float* lat = (const float*)d_in[0];
    const float* w1  = (const float*)d_in[1];
    const float* w2  = (const float*)d_in[2];
    const float* w3  = (const float*)d_in[3];
    const float* w4  = (const float*)d_in[4];
    float* out = (float*)d_out;
    float* ws  = (float*)d_ws;

    vq_main_kernel<<<256, 512, 0, stream>>>(lat, w1, w2, w3, w4, out, ws);
    vq_finalize_kernel<<<1, 256, 0, stream>>>(ws, out);
}

// Round 20
// 40.390 us; speedup vs baseline: 1.0183x; 1.0183x over previous
//
#include <hip/hip_runtime.h>
#include <stdint.h>

typedef __attribute__((ext_vector_type(8))) short short8;
typedef __attribute__((ext_vector_type(4))) float f32x4;

#define BIG 4.0f   // score shift: s' = BIG - 0.5||w||^2 + dot > 0 always

// fp32 -> bf16 bits, round-to-nearest-even
static __device__ __forceinline__ short f2bf(float f) {
    union { float f; uint32_t u; } v; v.f = f;
    uint32_t u = v.u;
    return (short)((u + 0x7FFFu + ((u >> 16) & 1u)) >> 16);
}

// ws layout: ws[4096 .. 4096+256) per-block loss partials.

// Main fused VQ (R17 structure, prep folded in, conflict-free convert).
// 256 blocks x 512 threads (8 waves); full 128 KB codebook converted
// fp32->bf16 IN-BLOCK into fragment-major LDS. Convert assignment is
// TRANSPOSED vs R19: lr2 = l&15 varies across each 16-lane subgroup so
// ds_write_b128 bank-quads (lr2%8)*4 spread over all 8 quads (R19 had all
// 16 lanes on one quad -> 1.8M conflict cycles). Norm via shfl_xor(16|32).
// ONE barrier. Write-behind + fused B-compute/A-write interleave as R17.
// launch_bounds arg2 CALIBRATION: 2 -> VGPR cap 128; 4 -> cap 64 + spill.
__global__ __launch_bounds__(512, 2)
void vq_main_kernel(const float* __restrict__ lat,
                    const float* __restrict__ w0, const float* __restrict__ w1,
                    const float* __restrict__ w2, const float* __restrict__ w3,
                    float* __restrict__ out, float* __restrict__ ws) {
    __shared__ __align__(16) short lw[65536];   // 128 KB codebook, fragment-major:
    // 16B unit (nt 0..31, ks 0..3, lane=lh*16+lr) at ((nt*4+ks)*64+lane)*16
    // holds code nt*16+lr, dims [ks*32+lh*8, +8)
    __shared__ float lwsq[512];                  // BIG - 0.5*||w||^2
    __shared__ float slsum[8];

    const int bid   = blockIdx.x;            // 0..255
    const int g     = bid >> 6;              // 0..3
    const int tbase = (bid & 63) * 512;      // token base within group
    const float* wg = (g == 0) ? w0 : (g == 1) ? w1 : (g == 2) ? w2 : w3;

    const int t    = threadIdx.x;            // 0..511
    const int wave = t >> 6;                 // 0..7
    const int l    = t & 63;
    const int lr   = l & 15;
    const int lh   = l >> 4;
    const int col  = (l & 31) * 4;
    const uint32_t invlr = 511 - lr;

    // ---- in-block codebook convert + stage (conflict-free) ----
    // pass p, wave w: codes c = p*128 + w*16 + (l&15); sub-pass sp:
    // unit u = (l>>4) + 4*sp. Write bank-quad = ((c&15)%8)*4 -> 8 quads x
    // 8 lanes = conflict-free. Lanes cl+{0,16,32,48} read a contiguous
    // 128B row-quarter per sp. Norm = shfl_xor(16)+shfl_xor(32).
    {
        const int cl = l & 15;
        const int ub = l >> 4;               // 0..3
        #pragma unroll
        for (int p = 0; p < 4; p++) {
            int c   = p * 128 + wave * 16 + cl;
            int nt2 = c >> 4;
            const float* src = wg + (size_t)c * 128;
            float s = 0.f;
            #pragma unroll
            for (int sp = 0; sp < 4; sp++) {
                int u   = ub + sp * 4;       // {ub, ub+4, ub+8, ub+12}
                int ks2 = u >> 2, lh2 = u & 3;
                float4 v0 = *(const float4*)(src + u * 8);
                float4 v1 = *(const float4*)(src + u * 8 + 4);
                s += v0.x*v0.x + v0.y*v0.y + v0.z*v0.z + v0.w*v0.w
                   + v1.x*v1.x + v1.y*v1.y + v1.z*v1.z + v1.w*v1.w;
                short8 b;
                b[0] = f2bf(v0.x); b[1] = f2bf(v0.y); b[2] = f2bf(v0.z); b[3] = f2bf(v0.w);
                b[4] = f2bf(v1.x); b[5] = f2bf(v1.y); b[6] = f2bf(v1.z); b[7] = f2bf(v1.w);
                *(short8*)((char*)lw +
                    (size_t)(((nt2 * 4 + ks2) * 64 + lh2 * 16 + cl) * 16)) = b;
            }
            s += __shfl_xor(s, 16);
            s += __shfl_xor(s, 32);
            if (ub == 0) lwsq[c] = BIG - 0.5f * s;
        }
    }

    const char* lwb = (const char*)lw + l * 16;
    const int wtok = tbase + wave * 64;

    auto load_convert = [&](short8 (&fr)[2][4], float (&xsp)[2], int wt) {
        #pragma unroll
        for (int mt = 0; mt < 2; mt++) {
            int token = wt + mt * 16 + lr;
            const float* xp = lat + (size_t)token * 512 + g * 128 + lh * 8;
            float part = 0.f;
            #pragma unroll
            for (int ks = 0; ks < 4; ks++) {
                float4 v0 = *(const float4*)(xp + ks * 32);
                float4 v1 = *(const float4*)(xp + ks * 32 + 4);
                part += v0.x*v0.x + v0.y*v0.y + v0.z*v0.z + v0.w*v0.w
                      + v1.x*v1.x + v1.y*v1.y + v1.z*v1.z + v1.w*v1.w;
                short8 a;
                a[0] = f2bf(v0.x); a[1] = f2bf(v0.y); a[2] = f2bf(v0.z); a[3] = f2bf(v0.w);
                a[4] = f2bf(v1.x); a[5] = f2bf(v1.y); a[6] = f2bf(v1.z); a[7] = f2bf(v1.w);
                fr[mt][ks] = a;
            }
            part += __shfl_xor(part, 16);
            part += __shfl_xor(part, 32);
            xsp[mt] = part;
        }
    };

    auto compute = [&](short8 (&af)[2][4], uint32_t (&rk)[8]) {
        short8 p0 = *(const short8*)(lwb);
        short8 p1 = *(const short8*)(lwb + 1024);
        short8 p2 = *(const short8*)(lwb + 2048);
        short8 p3 = *(const short8*)(lwb + 3072);
        float  ph = lwsq[lr];
        #pragma unroll 4
        for (int nt = 0; nt < 32; nt++) {
            short8 c0 = p0, c1 = p1, c2 = p2, c3 = p3;
            float  hn = ph;
            const char* nb = lwb + ((nt + 1) & 31) * 4096;
            p0 = *(const short8*)(nb);
            p1 = *(const short8*)(nb + 1024);
            p2 = *(const short8*)(nb + 2048);
            p3 = *(const short8*)(nb + 3072);
            ph = lwsq[(((nt + 1) & 31) << 4) + lr];
            const uint32_t invc = invlr - (uint32_t)(nt * 16);
            __builtin_amdgcn_s_setprio(1);
            f32x4 acc0 = {hn, hn, hn, hn};
            f32x4 acc1 = {hn, hn, hn, hn};
            acc0 = __builtin_amdgcn_mfma_f32_16x16x32_bf16(af[0][0], c0, acc0, 0, 0, 0);
            acc0 = __builtin_amdgcn_mfma_f32_16x16x32_bf16(af[0][1], c1, acc0, 0, 0, 0);
            acc0 = __builtin_amdgcn_mfma_f32_16x16x32_bf16(af[0][2], c2, acc0, 0, 0, 0);
            acc0 = __builtin_amdgcn_mfma_f32_16x16x32_bf16(af[0][3], c3, acc0, 0, 0, 0);
            acc1 = __builtin_amdgcn_mfma_f32_16x16x32_bf16(af[1][0], c0, acc1, 0, 0, 0);
            acc1 = __builtin_amdgcn_mfma_f32_16x16x32_bf16(af[1][1], c1, acc1, 0, 0, 0);
            acc1 = __builtin_amdgcn_mfma_f32_16x16x32_bf16(af[1][2], c2, acc1, 0, 0, 0);
            acc1 = __builtin_amdgcn_mfma_f32_16x16x32_bf16(af[1][3], c3, acc1, 0, 0, 0);
            __builtin_amdgcn_s_setprio(0);
            #pragma unroll
            for (int r = 0; r < 4; r++) {
                rk[r]     = max(rk[r],     (__float_as_uint(acc0[r]) & 0xFFFFFE00u) | invc);
                rk[4 + r] = max(rk[4 + r], (__float_as_uint(acc1[r]) & 0xFFFFFE00u) | invc);
            }
        }
    };

    auto epilogue = [&](uint32_t (&rk)[8], float (&xsp)[2], int wt, float& acc_lsum) {
        int runidx[8];
        #pragma unroll
        for (int i = 0; i < 8; i++) {
            uint32_t k = rk[i];
            k = max(k, (uint32_t)__shfl_xor((int)k, 1));
            k = max(k, (uint32_t)__shfl_xor((int)k, 2));
            k = max(k, (uint32_t)__shfl_xor((int)k, 4));
            k = max(k, (uint32_t)__shfl_xor((int)k, 8));
            rk[i] = k;
            runidx[i] = 511 - (int)(k & 0x1FFu);
        }
        #pragma unroll
        for (int mt = 0; mt < 2; mt++) {
            #pragma unroll
            for (int r = 0; r < 4; r++) {
                int row = lh * 4 + r;
                float xs = __shfl(xsp[mt], (l & 48) | row);
                float val = __uint_as_float(rk[mt * 4 + r] & 0xFFFFFE00u);
                if (lr == 0) acc_lsum += xs + 2.f * BIG - 2.f * val;
            }
        }
        #pragma unroll
        for (int it = 0; it < 16; it++) {
            const int j0 = it * 2, j1 = it * 2 + 1;
            int idx0 = __shfl(runidx[((j0 >> 4) << 2) | (j0 & 3)], ((j0 >> 2) & 3) << 4);
            int idx1 = __shfl(runidx[((j1 >> 4) << 2) | (j1 & 3)], ((j1 >> 2) & 3) << 4);
            int idx  = (l >= 32) ? idx1 : idx0;
            int tloc = it * 2 + (l >> 5);
            float4 v = *(const float4*)(wg + (size_t)idx * 128 + col);
            *(float4*)(out + (size_t)(wt + tloc) * 512 + g * 128 + col) = v;
        }
    };

    short8 fA[2][4], fB[2][4];
    float  xspA[2], xspB[2];
    uint32_t kA[8], kB[8];
    #pragma unroll
    for (int i = 0; i < 8; i++) { kA[i] = 0u; kB[i] = 0u; }

    load_convert(fA, xspA, wtok);        // overlaps codebook convert drain
    __syncthreads();                     // codebook + lwsq resident (only barrier)

    float lsum = 0.f;
    compute(fA, kA);

    // ---- issue batch-B raw loads; they fly during A's reduce + B convert ----
    float4 raw[16];
    #pragma unroll
    for (int mt = 0; mt < 2; mt++) {
        #pragma unroll
        for (int ks = 0; ks < 4; ks++) {
            const float* xp = lat + (size_t)(wtok + 32 + mt * 16 + lr) * 512
                            + g * 128 + lh * 8 + ks * 32;
            raw[mt * 8 + ks * 2]     = *(const float4*)(xp);
            raw[mt * 8 + ks * 2 + 1] = *(const float4*)(xp + 4);
        }
    }

    // ---- argmax + loss for batch A (overlaps raw-load flight) ----
    int runidxA[8];
    #pragma unroll
    for (int i = 0; i < 8; i++) {
        uint32_t k = kA[i];
        k = max(k, (uint32_t)__shfl_xor((int)k, 1));
        k = max(k, (uint32_t)__shfl_xor((int)k, 2));
        k = max(k, (uint32_t)__shfl_xor((int)k, 4));
        k = max(k, (uint32_t)__shfl_xor((int)k, 8));
        kA[i] = k;
        runidxA[i] = 511 - (int)(k & 0x1FFu);
    }
    #pragma unroll
    for (int mt = 0; mt < 2; mt++) {
        #pragma unroll
        for (int r = 0; r < 4; r++) {
            int row = lh * 4 + r;
            float xs = __shfl(xspA[mt], (l & 48) | row);
            float val = __uint_as_float(kA[mt * 4 + r] & 0xFFFFFE00u);
            if (lr == 0) lsum += xs + 2.f * BIG - 2.f * val;
        }
    }
    int widx[16];
    #pragma unroll
    for (int it = 0; it < 16; it++) {
        const int j0 = it * 2, j1 = it * 2 + 1;
        int idx0 = __shfl(runidxA[((j0 >> 4) << 2) | (j0 & 3)], ((j0 >> 2) & 3) << 4);
        int idx1 = __shfl(runidxA[((j1 >> 4) << 2) | (j1 & 3)], ((j1 >> 2) & 3) << 4);
        widx[it] = (l >= 32) ? idx1 : idx0;
    }

    // ---- convert batch B ----
    #pragma unroll
    for (int mt = 0; mt < 2; mt++) {
        float part = 0.f;
        #pragma unroll
        for (int ks = 0; ks < 4; ks++) {
            float4 v0 = raw[mt * 8 + ks * 2];
            float4 v1 = raw[mt * 8 + ks * 2 + 1];
            part += v0.x*v0.x + v0.y*v0.y + v0.z*v0.z + v0.w*v0.w
                  + v1.x*v1.x + v1.y*v1.y + v1.z*v1.z + v1.w*v1.w;
            short8 a;
            a[0] = f2bf(v0.x); a[1] = f2bf(v0.y); a[2] = f2bf(v0.z); a[3] = f2bf(v0.w);
            a[4] = f2bf(v1.x); a[5] = f2bf(v1.y); a[6] = f2bf(v1.z); a[7] = f2bf(v1.w);
            fB[mt][ks] = a;
        }
        part += __shfl_xor(part, 16);
        part += __shfl_xor(part, 32);
        xspB[mt] = part;
    }

    // ---- fused: compute batch B with batch-A q-writes interleaved ----
    {
        short8 p0 = *(const short8*)(lwb);
        short8 p1 = *(const short8*)(lwb + 1024);
        short8 p2 = *(const short8*)(lwb + 2048);
        short8 p3 = *(const short8*)(lwb + 3072);
        float  ph = lwsq[lr];
        float4 vb0, vb1;

#define FUSED_NT(nt)                                                           \
        {                                                                      \
            short8 c0 = p0, c1 = p1, c2 = p2, c3 = p3;                         \
            float  hn = ph;                                                    \
            const char* nb = lwb + (((nt) + 1) & 31) * 4096;                   \
            p0 = *(const short8*)(nb);                                         \
            p1 = *(const short8*)(nb + 1024);                                  \
            p2 = *(const short8*)(nb + 2048);                                  \
            p3 = *(const short8*)(nb + 3072);                                  \
            ph = lwsq[((((nt) + 1) & 31) << 4) + lr];                          \
            const uint32_t invc = invlr - (uint32_t)((nt) * 16);               \
            __builtin_amdgcn_s_setprio(1);                                     \
            f32x4 acc0 = {hn, hn, hn, hn};                                     \
            f32x4 acc1 = {hn, hn, hn, hn};                                     \
            acc0 = __builtin_amdgcn_mfma_f32_16x16x32_bf16(fB[0][0], c0, acc0, 0, 0, 0); \
            acc0 = __builtin_amdgcn_mfma_f32_16x16x32_bf16(fB[0][1], c1, acc0, 0, 0, 0); \
            acc0 = __builtin_amdgcn_mfma_f32_16x16x32_bf16(fB[0][2], c2, acc0, 0, 0, 0); \
            acc0 = __builtin_amdgcn_mfma_f32_16x16x32_bf16(fB[0][3], c3, acc0, 0, 0, 0); \
            acc1 = __builtin_amdgcn_mfma_f32_16x16x32_bf16(fB[1][0], c0, acc1, 0, 0, 0); \
            acc1 = __builtin_amdgcn_mfma_f32_16x16x32_bf16(fB[1][1], c1, acc1, 0, 0, 0); \
            acc1 = __builtin_amdgcn_mfma_f32_16x16x32_bf16(fB[1][2], c2, acc1, 0, 0, 0); \
            acc1 = __builtin_amdgcn_mfma_f32_16x16x32_bf16(fB[1][3], c3, acc1, 0, 0, 0); \
            __builtin_amdgcn_s_setprio(0);                                     \
            kB[0] = max(kB[0], (__float_as_uint(acc0[0]) & 0xFFFFFE00u) | invc); \
            kB[1] = max(kB[1], (__float_as_uint(acc0[1]) & 0xFFFFFE00u) | invc); \
            kB[2] = max(kB[2], (__float_as_uint(acc0[2]) & 0xFFFFFE00u) | invc); \
            kB[3] = max(kB[3], (__float_as_uint(acc0[3]) & 0xFFFFFE00u) | invc); \
            kB[4] = max(kB[4], (__float_as_uint(acc1[0]) & 0xFFFFFE00u) | invc); \
            kB[5] = max(kB[5], (__float_as_uint(acc1[1]) & 0xFFFFFE00u) | invc); \
            kB[6] = max(kB[6], (__float_as_uint(acc1[2]) & 0xFFFFFE00u) | invc); \
            kB[7] = max(kB[7], (__float_as_uint(acc1[3]) & 0xFFFFFE00u) | invc); \
            if (((nt) & 3) == 1) {                                             \
                const int it0 = ((nt) >> 2) * 2;                               \
                vb0 = *(const float4*)(wg + (size_t)widx[it0] * 128 + col);    \
                vb1 = *(const float4*)(wg + (size_t)widx[it0 + 1] * 128 + col);\
            }                                                                  \
            if (((nt) & 3) == 3) {                                             \
                const int it0 = ((nt) >> 2) * 2;                               \
                *(float4*)(out + (size_t)(wtok + it0 * 2 + (l >> 5)) * 512     \
                           + g * 128 + col) = vb0;                             \
                *(float4*)(out + (size_t)(wtok + (it0 + 1) * 2 + (l >> 5)) * 512 \
                           + g * 128 + col) = vb1;                             \
            }                                                                  \
        }
#define FUSED_4(n) FUSED_NT(n) FUSED_NT((n) + 1) FUSED_NT((n) + 2) FUSED_NT((n) + 3)
        FUSED_4(0)  FUSED_4(4)  FUSED_4(8)  FUSED_4(12)
        FUSED_4(16) FUSED_4(20) FUSED_4(24) FUSED_4(28)
#undef FUSED_4
#undef FUSED_NT
    }

    // ---- epilogue batch B (argmax, loss, q-writes) ----
    epilogue(kB, xspB, wtok + 32, lsum);

    // loss: wave partial -> one plain store per block
    lsum += __shfl_xor(lsum, 16);
    lsum += __shfl_xor(lsum, 32);
    if (l == 0) slsum[wave] = lsum;
    __syncthreads();
    if (t == 0) {
        float s = 0.f;
        #pragma unroll
        for (int i = 0; i < 8; i++) s += slsum[i];
        ws[4096 + bid] = s;
    }
}

// Finalize loss — reduce 256 per-block partials
__global__ void vq_finalize_kernel(const float* __restrict__ ws, float* __restrict__ out) {
    __shared__ float s4[4];
    float v = ws[4096 + threadIdx.x];
    #pragma unroll
    for (int m = 1; m < 64; m <<= 1) v += __shfl_xor(v, m);
    if ((threadIdx.x & 63) == 0) s4[threadIdx.x >> 6] = v;
    __syncthreads();
    if (threadIdx.x == 0)
        out[16777216] = 1.25f * (s4[0] + s4[1] + s4[2] + s4[3]) * (1.0f / 4194304.0f);
}

extern "C" void kernel_launch(void* const* d_in, const int* in_sizes, int n_in,
                              void* d_out, int out_size, void* d_ws, size_t ws_size,
                              hipStream_t stream) {
    const float* lat = (const float*)d_in[0];
    const float* w1  = (const float*)d_in[1];
    const float* w2  = (const float*)d_in[2];
    const float* w3  = (const float*)d_in[3];
    const float* w4  = (const float*)d_in[4];
    float* out = (float*)d_out;
    float* ws  = (float*)d_ws;

    vq_main_kernel<<<256, 512, 0, stream>>>(lat, w1, w2, w3, w4, out, ws);
    vq_finalize_kernel<<<1, 256, 0, stream>>>(ws, out);
}